// Round 1
// baseline (261.745 us; speedup 1.0000x reference)
//
#include <hip/hip_runtime.h>

// CoL: out[p] = sum_{q in 3x3} W[q-p] * L[bin(x_q), bin(x_p)] * x_q
// B=32 C=64 H=128 W=128, K=5 (L is 5x5), WH=3, zero pad.
// bin(x) = clamp((int)floor(x*5), 0, 4); x>=0 so trunc == floor.
// Memory-bound: ~268 MB min traffic. Each thread computes 4 contiguous
// pixels (float4 in/out). L table in LDS: 25 entries hit 25 distinct
// banks; same-index lanes broadcast -> effectively conflict-free gather.

namespace {
constexpr int H  = 128;
constexpr int WD = 128;
constexpr int PLANES = 32 * 64;            // B*C
constexpr int ROWS_PER_BLOCK = 16;
constexpr int TILES_PER_PLANE = H / ROWS_PER_BLOCK;   // 8
constexpr int THREADS = ROWS_PER_BLOCK * (WD / 4);    // 512
}

__global__ __launch_bounds__(THREADS) void col_kernel(
    const float* __restrict__ x, const float* __restrict__ Wf,
    const float* __restrict__ Lf, float* __restrict__ out)
{
    __shared__ float Ls[32];
    const int t = threadIdx.x;
    if (t < 25) Ls[t] = Lf[t];

    // W is 9 uniform floats -> registers (scalar-cached loads).
    float w[9];
    #pragma unroll
    for (int i = 0; i < 9; ++i) w[i] = Wf[i];

    __syncthreads();

    const int bid   = blockIdx.x;
    const int plane = bid >> 3;            // / TILES_PER_PLANE
    const int tile  = bid & 7;
    const int row   = tile * ROWS_PER_BLOCK + (t >> 5);
    const int col0  = (t & 31) << 2;       // 4 px per thread

    const float* xp = x + (size_t)plane * (H * WD);

    // 3 rows x 6 cols window covering the 3x3 nbhd of 4 pixels.
    float win[3][6];
    #pragma unroll
    for (int dr = 0; dr < 3; ++dr) {
        const int rr = row + dr - 1;
        const bool vr = (rr >= 0) && (rr < H);
        const float* rp = xp + rr * WD + col0;
        float4 c = make_float4(0.f, 0.f, 0.f, 0.f);
        float l = 0.f, r = 0.f;
        if (vr) {
            c = *(const float4*)rp;                   // 16B aligned
            if (col0 > 0)      l = rp[-1];
            if (col0 < WD - 4) r = rp[4];
        }
        win[dr][0] = l;   win[dr][1] = c.x; win[dr][2] = c.y;
        win[dr][3] = c.z; win[dr][4] = c.w; win[dr][5] = r;
    }

    // Bins for all 18 window values. Exact match to np: floor(x*5) clamp.
    int bq[3][6];
    #pragma unroll
    for (int dr = 0; dr < 3; ++dr) {
        #pragma unroll
        for (int i = 0; i < 6; ++i) {
            int b = (int)(win[dr][i] * 5.0f);   // x>=0: trunc==floor
            bq[dr][i] = (b > 4) ? 4 : b;
        }
    }

    // Center-pixel bins (the "p" side of L[bq, bp]).
    int bp[4];
    #pragma unroll
    for (int i = 0; i < 4; ++i) bp[i] = bq[1][i + 1];

    float acc[4] = {0.f, 0.f, 0.f, 0.f};
    #pragma unroll
    for (int dr = 0; dr < 3; ++dr) {
        #pragma unroll
        for (int dw = 0; dw < 3; ++dw) {
            const float wv = w[dr * 3 + dw];
            #pragma unroll
            for (int i = 0; i < 4; ++i) {
                const float xqv = win[dr][i + dw];
                const float lv  = Ls[bq[dr][i + dw] * 5 + bp[i]];
                acc[i] = fmaf(wv * xqv, lv, acc[i]);
            }
        }
    }

    float* op = out + (size_t)plane * (H * WD) + row * WD + col0;
    *(float4*)op = make_float4(acc[0], acc[1], acc[2], acc[3]);
}

extern "C" void kernel_launch(void* const* d_in, const int* in_sizes, int n_in,
                              void* d_out, int out_size, void* d_ws, size_t ws_size,
                              hipStream_t stream) {
    const float* x  = (const float*)d_in[0];   // input_tensor (B,C,H,W) fp32
    const float* Wf = (const float*)d_in[1];   // W (1,3,3) fp32
    const float* Lf = (const float*)d_in[2];   // L (5,5) fp32
    float* out = (float*)d_out;

    col_kernel<<<dim3(PLANES * TILES_PER_PLANE), dim3(THREADS), 0, stream>>>(
        x, Wf, Lf, out);
}

// Round 2
// 256.034 us; speedup vs baseline: 1.0223x; 1.0223x over previous
//
#include <hip/hip_runtime.h>

// CoL: out[p] = sum_{q in 3x3} W[q-p] * L[bin(x_q), bin(x_p)] * x_q
// B=32 C=64 H=128 W=128, L is 5x5, zero pad, bin(x)=clamp((int)(x*5),0,4).
//
// R2 design (latency-bound fix):
//  - LDS table WL[9][25] = W*L fused -> (dr,dw) selects a compile-time
//    immediate ds_read offset; per term = 1 v_add + ds_read + fmaf.
//  - 8 px/thread (2x float4): 72 independent gathers/wave for deep LDS
//    queue; window quantization amortized (30 values for 8 px).
//  - byte-scaled indices: bq20 = bin_q*20, bp4 = bin_p*4 precomputed.
//  - Each 25-dword sub-table spans 25 distinct banks; same-address lanes
//    broadcast -> conflict-free gathers.

namespace {
constexpr int H  = 128;
constexpr int WD = 128;
constexpr int PLANES = 32 * 64;            // B*C = 2048
constexpr int ROWS_PER_BLOCK = 16;
constexpr int PX = 8;                      // pixels per thread
constexpr int THREADS = ROWS_PER_BLOCK * (WD / PX);   // 256
constexpr int TILES = H / ROWS_PER_BLOCK;  // 8
}

__global__ __launch_bounds__(THREADS) void col_kernel(
    const float* __restrict__ x, const float* __restrict__ Wf,
    const float* __restrict__ Lf, float* __restrict__ out)
{
    __shared__ float WL[9 * 25];           // WL[(dr*3+dw)*25 + bq*5 + bp]
    const int t = threadIdx.x;
    if (t < 225) WL[t] = Wf[t / 25] * Lf[t % 25];
    __syncthreads();

    const int plane = blockIdx.x >> 3;     // / TILES
    const int tile  = blockIdx.x & 7;
    const int row   = tile * ROWS_PER_BLOCK + (t >> 4);
    const int col0  = (t & 15) * PX;

    const float* xp = x + (size_t)plane * (H * WD);

    // 3 rows x 10 cols window covering the 3x3 nbhd of 8 pixels.
    float win[3][PX + 2];
    #pragma unroll
    for (int dr = 0; dr < 3; ++dr) {
        const int rr = row + dr - 1;
        const bool vr = (rr >= 0) && (rr < H);
        const float* rp = xp + rr * WD + col0;
        float4 c0 = make_float4(0.f, 0.f, 0.f, 0.f);
        float4 c1 = make_float4(0.f, 0.f, 0.f, 0.f);
        float l = 0.f, r = 0.f;
        if (vr) {
            c0 = *(const float4*)rp;               // 16B aligned
            c1 = *(const float4*)(rp + 4);
            if (col0 > 0)       l = rp[-1];
            if (col0 < WD - PX) r = rp[PX];
        }
        win[dr][0] = l;
        win[dr][1] = c0.x; win[dr][2] = c0.y; win[dr][3] = c0.z; win[dr][4] = c0.w;
        win[dr][5] = c1.x; win[dr][6] = c1.y; win[dr][7] = c1.z; win[dr][8] = c1.w;
        win[dr][9] = r;
    }

    // Quantize every window value; keep byte-scaled row index bq*20.
    int bq20[3][PX + 2];
    int bp4[PX];                           // center bins * 4 (byte offset)
    #pragma unroll
    for (int dr = 0; dr < 3; ++dr) {
        #pragma unroll
        for (int j = 0; j < PX + 2; ++j) {
            int b = (int)(win[dr][j] * 5.0f);   // x>=0: trunc==floor
            b = (b > 4) ? 4 : b;
            bq20[dr][j] = b * 20;
            if (dr == 1 && j >= 1 && j <= PX) bp4[j - 1] = b * 4;
        }
    }

    const char* wlb = (const char*)WL;
    float acc[PX];
    #pragma unroll
    for (int i = 0; i < PX; ++i) acc[i] = 0.f;

    #pragma unroll
    for (int dr = 0; dr < 3; ++dr) {
        #pragma unroll
        for (int dw = 0; dw < 3; ++dw) {
            #pragma unroll
            for (int i = 0; i < PX; ++i) {
                // addr = WL + bq*20 + bp*4, + immediate (dr*3+dw)*100
                const float lw = *(const float*)(
                    wlb + (bq20[dr][i + dw] + bp4[i] + (dr * 3 + dw) * 100));
                acc[i] = fmaf(lw, win[dr][i + dw], acc[i]);
            }
        }
    }

    float* op = out + (size_t)plane * (H * WD) + row * WD + col0;
    *(float4*)op       = make_float4(acc[0], acc[1], acc[2], acc[3]);
    *(float4*)(op + 4) = make_float4(acc[4], acc[5], acc[6], acc[7]);
}

extern "C" void kernel_launch(void* const* d_in, const int* in_sizes, int n_in,
                              void* d_out, int out_size, void* d_ws, size_t ws_size,
                              hipStream_t stream) {
    const float* x  = (const float*)d_in[0];   // input_tensor (B,C,H,W) fp32
    const float* Wf = (const float*)d_in[1];   // W (1,3,3) fp32
    const float* Lf = (const float*)d_in[2];   // L (5,5) fp32
    float* out = (float*)d_out;

    col_kernel<<<dim3(PLANES * TILES), dim3(THREADS), 0, stream>>>(x, Wf, Lf, out);
}